// Round 3
// baseline (626.002 us; speedup 1.0000x reference)
//
#include <hip/hip_runtime.h>
#include <hip/hip_bf16.h>

#define NR 8192
#define WF 128

typedef short bf16x8 __attribute__((ext_vector_type(8)));
typedef float f32x4 __attribute__((ext_vector_type(4)));

static __device__ __forceinline__ unsigned int f2bf(float f) {
    unsigned int u = __float_as_uint(f);
    return (u + 0x7fffu + ((u >> 16) & 1u)) >> 16;
}
// works with *addr initialized to 0xFFFFFFFF (-NaN): int-max beats -1 for v>=0,
// uint-min beats UINT_MAX for v<0; mixed-sign interleavings keep the true max.
static __device__ __forceinline__ void atomicMaxF(float* addr, float v) {
    if (v >= 0.f) atomicMax((int*)addr, __float_as_int(v));
    else          atomicMin((unsigned int*)addr, __float_as_uint(v));
}
static __device__ __forceinline__ float lrelu(float x) { return x > 0.f ? x : 0.01f * x; }

// ---- k_proj: h = emb[inSen] @ W ; f_src/f_dst ; maxfd (atomic) ; hB (bf16 B-frags) ----
// hB layout: [colblk kb (256)][featgrp nf (8)][lane (64)][8 bf16]; lane = fx + 16*quad
// holds h^T[nf*16+fx][kb*32 + quad*8 + j], j=0..7.  Block = 16 rows (half a colblk).
__global__ __launch_bounds__(256) void k_proj(
    const int* __restrict__ inSen, const float* __restrict__ emb,
    const float* __restrict__ W, const float* __restrict__ a_src,
    const float* __restrict__ a_dst, float* __restrict__ f_src,
    float* __restrict__ f_dst, float* __restrict__ maxfd,
    unsigned short* __restrict__ hB)
{
    __shared__ float ht[16 * 132];
    const int t = threadIdx.x;
    const int f = t & 127, rh = t >> 7;     // feature, row-half (8 rows each)
    const int i0 = blockIdx.x * 16;

    int wd[8];
    #pragma unroll
    for (int r = 0; r < 8; ++r) wd[r] = inSen[i0 + rh * 8 + r];
    float h[8];
    #pragma unroll
    for (int r = 0; r < 8; ++r) h[r] = 0.f;

    for (int k4 = 0; k4 < 32; ++k4) {
        const float w0 = W[(k4 * 4 + 0) * WF + f];
        const float w1 = W[(k4 * 4 + 1) * WF + f];
        const float w2 = W[(k4 * 4 + 2) * WF + f];
        const float w3 = W[(k4 * 4 + 3) * WF + f];
        #pragma unroll
        for (int r = 0; r < 8; ++r) {
            float4 ev = ((const float4*)(emb + (size_t)wd[r] * 128))[k4];
            h[r] += ev.x * w0 + ev.y * w1 + ev.z * w2 + ev.w * w3;
        }
    }
    #pragma unroll
    for (int r = 0; r < 8; ++r) ht[(rh * 8 + r) * 132 + f] = h[r];
    __syncthreads();

    if (t < 16) {
        float s = 0.f, d = 0.f;
        for (int k4 = 0; k4 < 32; ++k4) {
            float4 hv = *(const float4*)(ht + t * 132 + k4 * 4);
            float4 as = ((const float4*)a_src)[k4];
            float4 ad = ((const float4*)a_dst)[k4];
            s += hv.x * as.x + hv.y * as.y + hv.z * as.z + hv.w * as.w;
            d += hv.x * ad.x + hv.y * ad.y + hv.z * ad.z + hv.w * ad.w;
        }
        f_src[i0 + t] = s;
        f_dst[i0 + t] = d;
        float dm = d;
        #pragma unroll
        for (int o = 1; o < 16; o <<= 1) dm = fmaxf(dm, __shfl_xor(dm, o));
        if (t == 0) atomicMaxF(maxfd, dm);
    }
    // hB fragment write: this block fills quads {half*2, half*2+1} of colblk kb
    {
        const int kb = blockIdx.x >> 1, half = blockIdx.x & 1;
        const int nf = t >> 5, l32 = t & 31;
        const int qloc = l32 >> 4, fx = l32 & 15;
        const int lane = (half * 2 + qloc) * 16 + fx;
        const float* hp = ht + (qloc * 8) * 132 + nf * 16 + fx;
        uint4 v;
        v.x = f2bf(hp[0 * 132]) | (f2bf(hp[1 * 132]) << 16);
        v.y = f2bf(hp[2 * 132]) | (f2bf(hp[3 * 132]) << 16);
        v.z = f2bf(hp[4 * 132]) | (f2bf(hp[5 * 132]) << 16);
        v.w = f2bf(hp[6 * 132]) | (f2bf(hp[7 * 132]) << 16);
        *(uint4*)(hB + ((size_t)kb * 8 + nf) * 512 + lane * 8) = v;
    }
}

// ---- k_adj v4: one row per WAVE. f_dst staged in LDS (keeps vmcnt stream pure-adj; ----
// vmcnt retires in issue order, so mixing L2 f_dst loads with HBM adj loads poisons
// the prefetch). adj via distance-8 register ring (8 KB/wave in flight, ~1300 cy cover
// vs ~900 cy HBM latency). maskG format: word kb = cols [kb*32,+32), bit = col%32.
static __device__ __forceinline__ void adj_chunk(
    int c, int4 a, const float* __restrict__ fdl, int lane, int row, int sl,
    float fs, float C, int shl,
    unsigned int* __restrict__ mrow, float& sum)
{
    const float4 f = *(const float4*)(fdl + c * 256 + 4 * lane);
    const bool m0 = a.x > 0, m1 = a.y > 0, m2 = a.z > 0, m3 = a.w > 0;
    float p0 = m0 ? __expf(lrelu(fs + f.x) - C) : 0.f;
    float p1 = m1 ? __expf(lrelu(fs + f.y) - C) : 0.f;
    float p2 = m2 ? __expf(lrelu(fs + f.z) - C) : 0.f;
    float p3 = m3 ? __expf(lrelu(fs + f.w) - C) : 0.f;
    unsigned int nib = (m0 ? 1u : 0u) | (m1 ? 2u : 0u) | (m2 ? 4u : 0u) | (m3 ? 8u : 0u);
    float ssum = p0 + p1 + p2 + p3;
    if (c == (row >> 8)) {                      // wave-uniform: diagonal lives here
        if (lane == ((row & 255) >> 2)) {
            const int jd = row & 3;
            const int aj = jd == 0 ? a.x : jd == 1 ? a.y : jd == 2 ? a.z : a.w;
            const float fj = jd == 0 ? f.x : jd == 1 ? f.y : jd == 2 ? f.z : f.w;
            const bool mo = aj > 0, mn = (aj + sl) > 0;
            if (mn != mo) {
                const float pd = __expf(lrelu(fs + fj) - C);
                if (mn) { nib |= 1u << jd; ssum += pd; }
                else    { nib &= ~(1u << jd); ssum -= pd; }
            }
        }
    }
    sum += ssum;
    // pack 8 lanes' nibbles -> one u32 mask word (bit = col%32), 8 words per 256-col chunk
    unsigned int v = nib << shl;
    v |= __shfl_xor(v, 1);
    v |= __shfl_xor(v, 2);
    v |= __shfl_xor(v, 4);
    if ((lane & 7) == 0) mrow[c * 8 + (lane >> 3)] = v;
}

__global__ __launch_bounds__(256, 4) void k_adj(
    const int* __restrict__ adj, const int* __restrict__ slP,
    const float* __restrict__ f_src, const float* __restrict__ f_dst,
    const float* __restrict__ maxfd, unsigned int* __restrict__ maskG,
    float* __restrict__ invl)
{
    __shared__ float fdl[NR];
    const int t = threadIdx.x, lane = t & 63, w = t >> 6;
    const int row = blockIdx.x * 4 + w;
    const int sl = slP[0];
    const int* __restrict__ ap = adj + (size_t)row * NR + 4 * lane;

    // issue the adj prefetch ring FIRST (its ~900 cy hides under the fdl stage + barrier)
    int4 a0 = *(const int4*)(ap + 0 * 256);
    int4 a1 = *(const int4*)(ap + 1 * 256);
    int4 a2 = *(const int4*)(ap + 2 * 256);
    int4 a3 = *(const int4*)(ap + 3 * 256);
    int4 a4 = *(const int4*)(ap + 4 * 256);
    int4 a5 = *(const int4*)(ap + 5 * 256);
    int4 a6 = *(const int4*)(ap + 6 * 256);
    int4 a7 = *(const int4*)(ap + 7 * 256);

    #pragma unroll
    for (int i = 0; i < 8; ++i)
        *(float4*)(fdl + (i * 256 + t) * 4) = *(const float4*)(f_dst + (i * 256 + t) * 4);

    const float fs = f_src[row];
    const float C = lrelu(fs + maxfd[0]);
    unsigned int* __restrict__ mrow = maskG + (size_t)row * 256;
    const int shl = 4 * (lane & 7);
    float sum = 0.f;
    __syncthreads();

    #define ADJC(c, reg) adj_chunk((c), (reg), fdl, lane, row, sl, fs, C, shl, mrow, sum)
    #pragma unroll 1
    for (int g = 0; g < 24; g += 8) {
        ADJC(g + 0, a0); a0 = *(const int4*)(ap + (g +  8) * 256);
        ADJC(g + 1, a1); a1 = *(const int4*)(ap + (g +  9) * 256);
        ADJC(g + 2, a2); a2 = *(const int4*)(ap + (g + 10) * 256);
        ADJC(g + 3, a3); a3 = *(const int4*)(ap + (g + 11) * 256);
        ADJC(g + 4, a4); a4 = *(const int4*)(ap + (g + 12) * 256);
        ADJC(g + 5, a5); a5 = *(const int4*)(ap + (g + 13) * 256);
        ADJC(g + 6, a6); a6 = *(const int4*)(ap + (g + 14) * 256);
        ADJC(g + 7, a7); a7 = *(const int4*)(ap + (g + 15) * 256);
    }
    ADJC(24, a0); ADJC(25, a1); ADJC(26, a2); ADJC(27, a3);
    ADJC(28, a4); ADJC(29, a5); ADJC(30, a6); ADJC(31, a7);
    #undef ADJC

    #pragma unroll
    for (int o = 1; o < 64; o <<= 1) sum += __shfl_xor(sum, o);
    if (lane == 0) invl[row] = 1.0f / sum;
}

// ---- k_att v3: 8-wave block = 1 strip (16 rows), wave = 1024-col K-split. ------------
// Latency-structured K-loop: hB frag loads hoisted to iteration top; f_dst and mask
// register-prefetched one step ahead, so the exp/pack/store phase (independent of hB)
// runs between bfr issue and the MFMAs that consume it. Block LDS reduce, direct
// sent store (no atomics, no memset).
__global__ __launch_bounds__(512, 4) void k_att(
    const unsigned int* __restrict__ maskG, const float* __restrict__ f_src,
    const float* __restrict__ f_dst, const float* __restrict__ maxfd,
    const float* __restrict__ invl, const unsigned short* __restrict__ hB,
    float* __restrict__ att, float* __restrict__ sent)
{
    __shared__ float red[8][2048];
    const int t = threadIdx.x;
    const int lane = t & 63, w = t >> 6;
    const int strip = blockIdx.x;             // 512 strips; block covers all 8 K-splits
    const int i0 = strip * 16;
    const int fx = lane & 15, quad = lane >> 4;
    const int row = i0 + fx;
    const float fs = f_src[row];
    const float C = lrelu(fs + maxfd[0]);
    const float il = invl[row];
    float* __restrict__ ar = att + (size_t)row * NR;
    const unsigned int* __restrict__ mrow = maskG + (size_t)row * 256;
    f32x4 acc[8] = {};
    const int kb0 = w * 32;                   // wave's 32 col-blocks (1024 cols)
    const unsigned short* __restrict__ hp0 = hB + (size_t)kb0 * 4096 + lane * 8;
    const float* __restrict__ fp0 = f_dst + kb0 * 32 + quad * 8;

    uint4 mw = *(const uint4*)(mrow + kb0);   // mask words for group 0
    float4 fdA0 = *(const float4*)(fp0);      // fd for iter 0
    float4 fdA1 = *(const float4*)(fp0 + 4);

    #pragma unroll 1
    for (int g = 0; g < 8; ++g) {             // 8 groups x 4 col-blocks
        uint4 mw_n;
        if (g < 7) mw_n = *(const uint4*)(mrow + kb0 + (g + 1) * 4);
        #pragma unroll
        for (int j = 0; j < 4; ++j) {
            const int i = g * 4 + j;
            // 1) issue this iter's hB fragment loads (consumed by MFMA at the bottom)
            const unsigned short* hp = hp0 + (size_t)i * 4096;
            bf16x8 bfr[8];
            #pragma unroll
            for (int nf = 0; nf < 8; ++nf) bfr[nf] = *(const bf16x8*)(hp + nf * 512);
            // 2) prefetch next iter's fd
            float4 fdB0, fdB1;
            {
                const float* fpn = fp0 + (i + 1) * 32;
                fdB0 = *(const float4*)(fpn);
                fdB1 = *(const float4*)(fpn + 4);
            }
            // 3) exp/pack/store from ALREADY-RESIDENT fd (covers hB latency)
            const unsigned int mword = (j == 0) ? mw.x : (j == 1) ? mw.y
                                     : (j == 2) ? mw.z : mw.w;
            const unsigned int mbyte = (mword >> (quad * 8)) & 0xffu;
            const float fv[8] = {fdA0.x, fdA0.y, fdA0.z, fdA0.w,
                                 fdA1.x, fdA1.y, fdA1.z, fdA1.w};
            float p[8];
            #pragma unroll
            for (int jj = 0; jj < 8; ++jj)
                p[jj] = ((mbyte >> jj) & 1u) ? __expf(lrelu(fs + fv[jj]) - C) : 0.f;

            const int kk = (kb0 + i) * 32;
            const float4 w0 = make_float4(p[0] * il, p[1] * il, p[2] * il, p[3] * il);
            const float4 w1 = make_float4(p[4] * il, p[5] * il, p[6] * il, p[7] * il);
            *(float4*)(ar + kk + quad * 8) = w0;
            *(float4*)(ar + kk + quad * 8 + 4) = w1;

            union { uint4 u; bf16x8 v; } cv;
            cv.u.x = f2bf(p[0]) | (f2bf(p[1]) << 16);
            cv.u.y = f2bf(p[2]) | (f2bf(p[3]) << 16);
            cv.u.z = f2bf(p[4]) | (f2bf(p[5]) << 16);
            cv.u.w = f2bf(p[6]) | (f2bf(p[7]) << 16);
            // 4) MFMAs consume bfr (issued ~150-200 cy ago)
            #pragma unroll
            for (int nf = 0; nf < 8; ++nf)
                acc[nf] = __builtin_amdgcn_mfma_f32_16x16x32_bf16(cv.v, bfr[nf], acc[nf], 0, 0, 0);
            fdA0 = fdB0; fdA1 = fdB1;
        }
        if (g < 7) mw = mw_n;
    }
    // D layout (16x16x32): row = quad*4+reg (att row in strip), col = fx (feat in nf)
    #pragma unroll
    for (int reg = 0; reg < 4; ++reg) {
        #pragma unroll
        for (int nf = 0; nf < 8; ++nf)
            red[w][(quad * 4 + reg) * 128 + nf * 16 + fx] = acc[nf][reg];
    }
    __syncthreads();
    {
        const int e0 = t * 4;                 // 512 threads x 4 = 2048 = 16 rows x 128
        const int m = e0 >> 7, f0 = e0 & 127;
        const float vin = invl[i0 + m];
        float vv[4];
        #pragma unroll
        for (int j = 0; j < 4; ++j) {
            float s = 0.f;
            #pragma unroll
            for (int sx = 0; sx < 8; ++sx) s += red[sx][e0 + j];
            vv[j] = s * vin;
        }
        *(float4*)(sent + (size_t)(i0 + m) * WF + f0) = make_float4(vv[0], vv[1], vv[2], vv[3]);
    }
}

// ---- k_pool: per-block column max over 32 rows -> partial[256][128] (no atomics) ------
__global__ __launch_bounds__(256) void k_pool(
    const float* __restrict__ sent, float* __restrict__ partial)
{
    __shared__ float s[256];
    const int t = threadIdx.x;
    const int f = t & 127, rh = t >> 7;
    const int r0 = blockIdx.x * 32;
    float m = -1e30f;
    #pragma unroll
    for (int j = 0; j < 16; ++j)
        m = fmaxf(m, sent[(size_t)(r0 + j * 2 + rh) * WF + f]);
    s[t] = m;
    __syncthreads();
    if (t < 128) partial[blockIdx.x * 128 + t] = fmaxf(s[t], s[t + 128]);
}

// ---- k_label: final pool max + classifier ---------------------------------------------
__global__ __launch_bounds__(128) void k_label(
    const float* __restrict__ partial, const float* __restrict__ cls_W,
    const float* __restrict__ cls_b, float* __restrict__ pool,
    float* __restrict__ label)
{
    __shared__ float s0[128], s1[128];
    const int t = threadIdx.x;
    float m = -1e30f;
    for (int b = 0; b < 256; ++b) m = fmaxf(m, partial[b * 128 + t]);
    pool[t] = m;
    s0[t] = m * cls_W[t * 2 + 0];
    s1[t] = m * cls_W[t * 2 + 1];
    __syncthreads();
    if (t == 0) {
        float z0 = cls_b[0], z1 = cls_b[1];
        for (int f = 0; f < 128; ++f) { z0 += s0[f]; z1 += s1[f]; }
        float mm = fmaxf(z0, z1);
        float e0 = __expf(z0 - mm), e1 = __expf(z1 - mm);
        float inv = 1.0f / (e0 + e1);
        label[0] = e0 * inv;
        label[1] = e1 * inv;
    }
}

extern "C" void kernel_launch(void* const* d_in, const int* in_sizes, int n_in,
                              void* d_out, int out_size, void* d_ws, size_t ws_size,
                              hipStream_t stream)
{
    const int*   inSen    = (const int*)d_in[0];
    const int*   adj      = (const int*)d_in[1];
    const int*   selfLink = (const int*)d_in[2];
    const float* emb      = (const float*)d_in[3];
    const float* W        = (const float*)d_in[4];
    const float* a_src    = (const float*)d_in[5];
    const float* a_dst    = (const float*)d_in[6];
    const float* cls_W    = (const float*)d_in[7];
    const float* cls_b    = (const float*)d_in[8];

    float* out   = (float*)d_out;
    float* pool  = out;                         // 128
    float* att   = out + 128;                   // 8192*8192
    float* sent  = att + (size_t)NR * NR;       // 8192*128
    float* label = sent + (size_t)NR * WF;      // 2

    char* ws = (char*)d_ws;
    unsigned short* hB    = (unsigned short*)ws;               // 2 MB
    unsigned int*   maskG = (unsigned int*)(ws + (2u << 20));  // 8 MB
    float* f_src   = (float*)(ws + (10u << 20));               // 32 KB
    float* f_dst   = f_src + NR;                               // 32 KB
    float* invl    = f_dst + NR;                               // 32 KB
    float* maxfd   = invl + NR;                                // 4 B (pad to 64)
    float* partial = maxfd + 64;                               // 256*128 = 128 KB

    hipMemsetAsync(maxfd, 0xFF, 4, stream);    // -NaN init for atomicMaxF
    k_proj<<<NR / 16, 256, 0, stream>>>(inSen, emb, W, a_src, a_dst, f_src, f_dst, maxfd, hB);
    k_adj<<<NR / 4, 256, 0, stream>>>(adj, selfLink, f_src, f_dst, maxfd, maskG, invl);
    k_att<<<NR / 16, 512, 0, stream>>>(maskG, f_src, f_dst, maxfd, invl, hB, att, sent);
    k_pool<<<NR / 32, 256, 0, stream>>>(sent, partial);
    k_label<<<1, 128, 0, stream>>>(partial, cls_W, cls_b, pool, label);
}

// Round 4
// 595.978 us; speedup vs baseline: 1.0504x; 1.0504x over previous
//
#include <hip/hip_runtime.h>
#include <hip/hip_bf16.h>

#define NR 8192
#define WF 128

typedef short bf16x8 __attribute__((ext_vector_type(8)));
typedef float f32x4 __attribute__((ext_vector_type(4)));

static __device__ __forceinline__ unsigned int f2bf(float f) {
    unsigned int u = __float_as_uint(f);
    return (u + 0x7fffu + ((u >> 16) & 1u)) >> 16;
}
// works with *addr initialized to 0xFFFFFFFF (-NaN): int-max beats -1 for v>=0,
// uint-min beats UINT_MAX for v<0; mixed-sign interleavings keep the true max.
static __device__ __forceinline__ void atomicMaxF(float* addr, float v) {
    if (v >= 0.f) atomicMax((int*)addr, __float_as_int(v));
    else          atomicMin((unsigned int*)addr, __float_as_uint(v));
}
static __device__ __forceinline__ float lrelu(float x) { return x > 0.f ? x : 0.01f * x; }

// ---- k_proj: h = emb[inSen] @ W ; f_src/f_dst ; maxfd (atomic) ; hB (bf16 B-frags) ----
// hB layout: [colblk kb (256)][featgrp nf (8)][lane (64)][8 bf16]; lane = fx + 16*quad
// holds h^T[nf*16+fx][kb*32 + quad*8 + j], j=0..7.  Block = 16 rows (half a colblk).
__global__ __launch_bounds__(256) void k_proj(
    const int* __restrict__ inSen, const float* __restrict__ emb,
    const float* __restrict__ W, const float* __restrict__ a_src,
    const float* __restrict__ a_dst, float* __restrict__ f_src,
    float* __restrict__ f_dst, float* __restrict__ maxfd,
    unsigned short* __restrict__ hB)
{
    __shared__ float ht[16 * 132];
    const int t = threadIdx.x;
    const int f = t & 127, rh = t >> 7;     // feature, row-half (8 rows each)
    const int i0 = blockIdx.x * 16;

    int wd[8];
    #pragma unroll
    for (int r = 0; r < 8; ++r) wd[r] = inSen[i0 + rh * 8 + r];
    float h[8];
    #pragma unroll
    for (int r = 0; r < 8; ++r) h[r] = 0.f;

    for (int k4 = 0; k4 < 32; ++k4) {
        const float w0 = W[(k4 * 4 + 0) * WF + f];
        const float w1 = W[(k4 * 4 + 1) * WF + f];
        const float w2 = W[(k4 * 4 + 2) * WF + f];
        const float w3 = W[(k4 * 4 + 3) * WF + f];
        #pragma unroll
        for (int r = 0; r < 8; ++r) {
            float4 ev = ((const float4*)(emb + (size_t)wd[r] * 128))[k4];
            h[r] += ev.x * w0 + ev.y * w1 + ev.z * w2 + ev.w * w3;
        }
    }
    #pragma unroll
    for (int r = 0; r < 8; ++r) ht[(rh * 8 + r) * 132 + f] = h[r];
    __syncthreads();

    if (t < 16) {
        float s = 0.f, d = 0.f;
        for (int k4 = 0; k4 < 32; ++k4) {
            float4 hv = *(const float4*)(ht + t * 132 + k4 * 4);
            float4 as = ((const float4*)a_src)[k4];
            float4 ad = ((const float4*)a_dst)[k4];
            s += hv.x * as.x + hv.y * as.y + hv.z * as.z + hv.w * as.w;
            d += hv.x * ad.x + hv.y * ad.y + hv.z * ad.z + hv.w * ad.w;
        }
        f_src[i0 + t] = s;
        f_dst[i0 + t] = d;
        float dm = d;
        #pragma unroll
        for (int o = 1; o < 16; o <<= 1) dm = fmaxf(dm, __shfl_xor(dm, o));
        if (t == 0) atomicMaxF(maxfd, dm);
    }
    // hB fragment write: this block fills quads {half*2, half*2+1} of colblk kb
    {
        const int kb = blockIdx.x >> 1, half = blockIdx.x & 1;
        const int nf = t >> 5, l32 = t & 31;
        const int qloc = l32 >> 4, fx = l32 & 15;
        const int lane = (half * 2 + qloc) * 16 + fx;
        const float* hp = ht + (qloc * 8) * 132 + nf * 16 + fx;
        uint4 v;
        v.x = f2bf(hp[0 * 132]) | (f2bf(hp[1 * 132]) << 16);
        v.y = f2bf(hp[2 * 132]) | (f2bf(hp[3 * 132]) << 16);
        v.z = f2bf(hp[4 * 132]) | (f2bf(hp[5 * 132]) << 16);
        v.w = f2bf(hp[6 * 132]) | (f2bf(hp[7 * 132]) << 16);
        *(uint4*)(hB + ((size_t)kb * 8 + nf) * 512 + lane * 8) = v;
    }
}

// ---- k_adj v4: one row per WAVE. f_dst staged in LDS (keeps vmcnt stream pure-adj);
// adj via distance-8 register ring (8 KB/wave in flight, ~1300 cy cover vs ~900 cy HBM
// latency). maskG format: word kb = cols [kb*32,+32), bit = col%32.
static __device__ __forceinline__ void adj_chunk(
    int c, int4 a, const float* __restrict__ fdl, int lane, int row, int sl,
    float fs, float C, int shl,
    unsigned int* __restrict__ mrow, float& sum)
{
    const float4 f = *(const float4*)(fdl + c * 256 + 4 * lane);
    const bool m0 = a.x > 0, m1 = a.y > 0, m2 = a.z > 0, m3 = a.w > 0;
    float p0 = m0 ? __expf(lrelu(fs + f.x) - C) : 0.f;
    float p1 = m1 ? __expf(lrelu(fs + f.y) - C) : 0.f;
    float p2 = m2 ? __expf(lrelu(fs + f.z) - C) : 0.f;
    float p3 = m3 ? __expf(lrelu(fs + f.w) - C) : 0.f;
    unsigned int nib = (m0 ? 1u : 0u) | (m1 ? 2u : 0u) | (m2 ? 4u : 0u) | (m3 ? 8u : 0u);
    float ssum = p0 + p1 + p2 + p3;
    if (c == (row >> 8)) {                      // wave-uniform: diagonal lives here
        if (lane == ((row & 255) >> 2)) {
            const int jd = row & 3;
            const int aj = jd == 0 ? a.x : jd == 1 ? a.y : jd == 2 ? a.z : a.w;
            const float fj = jd == 0 ? f.x : jd == 1 ? f.y : jd == 2 ? f.z : f.w;
            const bool mo = aj > 0, mn = (aj + sl) > 0;
            if (mn != mo) {
                const float pd = __expf(lrelu(fs + fj) - C);
                if (mn) { nib |= 1u << jd; ssum += pd; }
                else    { nib &= ~(1u << jd); ssum -= pd; }
            }
        }
    }
    sum += ssum;
    // pack 8 lanes' nibbles -> one u32 mask word (bit = col%32), 8 words per 256-col chunk
    unsigned int v = nib << shl;
    v |= __shfl_xor(v, 1);
    v |= __shfl_xor(v, 2);
    v |= __shfl_xor(v, 4);
    if ((lane & 7) == 0) mrow[c * 8 + (lane >> 3)] = v;
}

__global__ __launch_bounds__(256, 4) void k_adj(
    const int* __restrict__ adj, const int* __restrict__ slP,
    const float* __restrict__ f_src, const float* __restrict__ f_dst,
    const float* __restrict__ maxfd, unsigned int* __restrict__ maskG,
    float* __restrict__ invl)
{
    __shared__ float fdl[NR];
    const int t = threadIdx.x, lane = t & 63, w = t >> 6;
    const int row = blockIdx.x * 4 + w;
    const int sl = slP[0];
    const int* __restrict__ ap = adj + (size_t)row * NR + 4 * lane;

    // issue the adj prefetch ring FIRST (its ~900 cy hides under the fdl stage + barrier)
    int4 a0 = *(const int4*)(ap + 0 * 256);
    int4 a1 = *(const int4*)(ap + 1 * 256);
    int4 a2 = *(const int4*)(ap + 2 * 256);
    int4 a3 = *(const int4*)(ap + 3 * 256);
    int4 a4 = *(const int4*)(ap + 4 * 256);
    int4 a5 = *(const int4*)(ap + 5 * 256);
    int4 a6 = *(const int4*)(ap + 6 * 256);
    int4 a7 = *(const int4*)(ap + 7 * 256);

    #pragma unroll
    for (int i = 0; i < 8; ++i)
        *(float4*)(fdl + (i * 256 + t) * 4) = *(const float4*)(f_dst + (i * 256 + t) * 4);

    const float fs = f_src[row];
    const float C = lrelu(fs + maxfd[0]);
    unsigned int* __restrict__ mrow = maskG + (size_t)row * 256;
    const int shl = 4 * (lane & 7);
    float sum = 0.f;
    __syncthreads();

    #define ADJC(c, reg) adj_chunk((c), (reg), fdl, lane, row, sl, fs, C, shl, mrow, sum)
    #pragma unroll 1
    for (int g = 0; g < 24; g += 8) {
        ADJC(g + 0, a0); a0 = *(const int4*)(ap + (g +  8) * 256);
        ADJC(g + 1, a1); a1 = *(const int4*)(ap + (g +  9) * 256);
        ADJC(g + 2, a2); a2 = *(const int4*)(ap + (g + 10) * 256);
        ADJC(g + 3, a3); a3 = *(const int4*)(ap + (g + 11) * 256);
        ADJC(g + 4, a4); a4 = *(const int4*)(ap + (g + 12) * 256);
        ADJC(g + 5, a5); a5 = *(const int4*)(ap + (g + 13) * 256);
        ADJC(g + 6, a6); a6 = *(const int4*)(ap + (g + 14) * 256);
        ADJC(g + 7, a7); a7 = *(const int4*)(ap + (g + 15) * 256);
    }
    ADJC(24, a0); ADJC(25, a1); ADJC(26, a2); ADJC(27, a3);
    ADJC(28, a4); ADJC(29, a5); ADJC(30, a6); ADJC(31, a7);
    #undef ADJC

    #pragma unroll
    for (int o = 1; o < 64; o <<= 1) sum += __shfl_xor(sum, o);
    if (lane == 0) invl[row] = 1.0f / sum;
}

// ---- k_att v4: round-2 v2 structure + f_dst in LDS (aliased with red; fdl phase ends
// before red phase begins) + fused pool-partial epilogue. 8-wave block = 1 strip
// (16 rows), wave = 1024-col K-split. Direct sent store, no atomics, no memset.
__global__ __launch_bounds__(512, 4) void k_att(
    const unsigned int* __restrict__ maskG, const float* __restrict__ f_src,
    const float* __restrict__ f_dst, const float* __restrict__ maxfd,
    const float* __restrict__ invl, const unsigned short* __restrict__ hB,
    float* __restrict__ att, float* __restrict__ sent, float* __restrict__ partial)
{
    __shared__ float red[8][2048];            // 64 KB; red[0..3] doubles as fdl in phase 1
    float* fdl = &red[0][0];                  // 8192 floats
    const int t = threadIdx.x;
    const int lane = t & 63, w = t >> 6;
    const int strip = blockIdx.x;             // 512 strips; block covers all 8 K-splits
    const int i0 = strip * 16;
    const int fx = lane & 15, quad = lane >> 4;
    const int row = i0 + fx;

    #pragma unroll
    for (int i = 0; i < 4; ++i)
        *(float4*)(fdl + (i * 512 + t) * 4) = *(const float4*)(f_dst + (i * 512 + t) * 4);

    const float fs = f_src[row];
    const float C = lrelu(fs + maxfd[0]);
    const float il = invl[row];
    float* __restrict__ ar = att + (size_t)row * NR;
    const unsigned int* __restrict__ mrow = maskG + (size_t)row * 256;
    f32x4 acc[8] = {};
    const int k0 = w * 1024;
    __syncthreads();

    for (int kk4 = k0; kk4 < k0 + 1024; kk4 += 128) {
        const uint4 mw = *(const uint4*)(mrow + (kk4 >> 5));
        const unsigned int mwa[4] = {mw.x, mw.y, mw.z, mw.w};
        #pragma unroll
        for (int j4 = 0; j4 < 4; ++j4) {
            const int kk = kk4 + j4 * 32;
            const int kb = kk >> 5;
            const unsigned short* hp = hB + (size_t)kb * 4096 + lane * 8;
            bf16x8 bfr[8];
            #pragma unroll
            for (int nf = 0; nf < 8; ++nf) bfr[nf] = *(const bf16x8*)(hp + nf * 512);

            const unsigned int mbyte = (mwa[j4] >> (quad * 8)) & 0xffu;
            const float4 fd0 = *(const float4*)(fdl + kk + quad * 8);     // LDS broadcast
            const float4 fd1 = *(const float4*)(fdl + kk + quad * 8 + 4);
            const float fv[8] = {fd0.x, fd0.y, fd0.z, fd0.w, fd1.x, fd1.y, fd1.z, fd1.w};
            float p[8];
            #pragma unroll
            for (int j = 0; j < 8; ++j)
                p[j] = ((mbyte >> j) & 1u) ? __expf(lrelu(fs + fv[j]) - C) : 0.f;

            const float4 w0 = make_float4(p[0] * il, p[1] * il, p[2] * il, p[3] * il);
            const float4 w1 = make_float4(p[4] * il, p[5] * il, p[6] * il, p[7] * il);
            *(float4*)(ar + kk + quad * 8) = w0;
            *(float4*)(ar + kk + quad * 8 + 4) = w1;

            union { uint4 u; bf16x8 v; } cv;
            cv.u.x = f2bf(p[0]) | (f2bf(p[1]) << 16);
            cv.u.y = f2bf(p[2]) | (f2bf(p[3]) << 16);
            cv.u.z = f2bf(p[4]) | (f2bf(p[5]) << 16);
            cv.u.w = f2bf(p[6]) | (f2bf(p[7]) << 16);
            #pragma unroll
            for (int nf = 0; nf < 8; ++nf)
                acc[nf] = __builtin_amdgcn_mfma_f32_16x16x32_bf16(cv.v, bfr[nf], acc[nf], 0, 0, 0);
        }
    }
    __syncthreads();                          // all fdl reads done before red overwrites it
    // D layout (16x16x32): row = quad*4+reg (att row in strip), col = fx (feat in nf)
    #pragma unroll
    for (int reg = 0; reg < 4; ++reg) {
        #pragma unroll
        for (int nf = 0; nf < 8; ++nf)
            red[w][(quad * 4 + reg) * 128 + nf * 16 + fx] = acc[nf][reg];
    }
    __syncthreads();
    const int e0 = t * 4;                     // 512 threads x 4 = 2048 = 16 rows x 128
    const int m = e0 >> 7, f0 = e0 & 127;
    {
        const float vin = invl[i0 + m];
        float vv[4];
        #pragma unroll
        for (int j = 0; j < 4; ++j) {
            float s = 0.f;
            #pragma unroll
            for (int sx = 0; sx < 8; ++sx) s += red[sx][e0 + j];
            vv[j] = s * vin;
        }
        *(float4*)(sent + (size_t)(i0 + m) * WF + f0) = make_float4(vv[0], vv[1], vv[2], vv[3]);
        // stash vv in thread-exclusive slots (red[0][e0..e0+3] is read/written only by t)
        red[0][e0 + 0] = vv[0]; red[0][e0 + 1] = vv[1];
        red[0][e0 + 2] = vv[2]; red[0][e0 + 3] = vv[3];
    }
    __syncthreads();
    if (t < 128) {                            // column max over the strip's 16 rows
        float mx = red[0][t];
        #pragma unroll
        for (int mm = 1; mm < 16; ++mm) mx = fmaxf(mx, red[0][mm * 128 + t]);
        partial[strip * 128 + t] = mx;
    }
}

// ---- k_label: final pool max (512 strip partials) + classifier ------------------------
__global__ __launch_bounds__(128) void k_label(
    const float* __restrict__ partial, const float* __restrict__ cls_W,
    const float* __restrict__ cls_b, float* __restrict__ pool,
    float* __restrict__ label)
{
    __shared__ float s0[128], s1[128];
    const int t = threadIdx.x;
    float m0 = -1e30f, m1 = -1e30f, m2 = -1e30f, m3 = -1e30f;
    for (int b = 0; b < 512; b += 4) {
        m0 = fmaxf(m0, partial[(b + 0) * 128 + t]);
        m1 = fmaxf(m1, partial[(b + 1) * 128 + t]);
        m2 = fmaxf(m2, partial[(b + 2) * 128 + t]);
        m3 = fmaxf(m3, partial[(b + 3) * 128 + t]);
    }
    const float m = fmaxf(fmaxf(m0, m1), fmaxf(m2, m3));
    pool[t] = m;
    s0[t] = m * cls_W[t * 2 + 0];
    s1[t] = m * cls_W[t * 2 + 1];
    __syncthreads();
    if (t == 0) {
        float z0 = cls_b[0], z1 = cls_b[1];
        for (int f = 0; f < 128; ++f) { z0 += s0[f]; z1 += s1[f]; }
        float mm = fmaxf(z0, z1);
        float e0 = __expf(z0 - mm), e1 = __expf(z1 - mm);
        float inv = 1.0f / (e0 + e1);
        label[0] = e0 * inv;
        label[1] = e1 * inv;
    }
}

extern "C" void kernel_launch(void* const* d_in, const int* in_sizes, int n_in,
                              void* d_out, int out_size, void* d_ws, size_t ws_size,
                              hipStream_t stream)
{
    const int*   inSen    = (const int*)d_in[0];
    const int*   adj      = (const int*)d_in[1];
    const int*   selfLink = (const int*)d_in[2];
    const float* emb      = (const float*)d_in[3];
    const float* W        = (const float*)d_in[4];
    const float* a_src    = (const float*)d_in[5];
    const float* a_dst    = (const float*)d_in[6];
    const float* cls_W    = (const float*)d_in[7];
    const float* cls_b    = (const float*)d_in[8];

    float* out   = (float*)d_out;
    float* pool  = out;                         // 128
    float* att   = out + 128;                   // 8192*8192
    float* sent  = att + (size_t)NR * NR;       // 8192*128
    float* label = sent + (size_t)NR * WF;      // 2

    char* ws = (char*)d_ws;
    unsigned short* hB    = (unsigned short*)ws;               // 2 MB
    unsigned int*   maskG = (unsigned int*)(ws + (2u << 20));  // 8 MB
    float* f_src   = (float*)(ws + (10u << 20));               // 32 KB
    float* f_dst   = f_src + NR;                               // 32 KB
    float* invl    = f_dst + NR;                               // 32 KB
    float* maxfd   = invl + NR;                                // 4 B (pad to 64)
    float* partial = maxfd + 64;                               // 512*128 = 256 KB

    hipMemsetAsync(maxfd, 0xFF, 4, stream);    // -NaN init for atomicMaxF
    k_proj<<<NR / 16, 256, 0, stream>>>(inSen, emb, W, a_src, a_dst, f_src, f_dst, maxfd, hB);
    k_adj<<<NR / 4, 256, 0, stream>>>(adj, selfLink, f_src, f_dst, maxfd, maskG, invl);
    k_att<<<NR / 16, 512, 0, stream>>>(maskG, f_src, f_dst, maxfd, invl, hB, att, sent, partial);
    k_label<<<1, 128, 0, stream>>>(partial, cls_W, cls_b, pool, label);
}

// Round 5
// 585.800 us; speedup vs baseline: 1.0686x; 1.0174x over previous
//
#include <hip/hip_runtime.h>
#include <hip/hip_bf16.h>

#define NR 8192
#define WF 128
#define MSTRIDE 260   // mask LDS row stride in u32 (260%32=4 -> 2-way bank = free)

typedef short bf16x8 __attribute__((ext_vector_type(8)));
typedef float f32x4 __attribute__((ext_vector_type(4)));

static __device__ __forceinline__ unsigned int f2bf(float f) {
    unsigned int u = __float_as_uint(f);
    return (u + 0x7fffu + ((u >> 16) & 1u)) >> 16;
}
// works with *addr initialized to 0xFFFFFFFF (-NaN): int-max beats -1 for v>=0,
// uint-min beats UINT_MAX for v<0; mixed-sign interleavings keep the true max.
static __device__ __forceinline__ void atomicMaxF(float* addr, float v) {
    if (v >= 0.f) atomicMax((int*)addr, __float_as_int(v));
    else          atomicMin((unsigned int*)addr, __float_as_uint(v));
}
static __device__ __forceinline__ float lrelu(float x) { return x > 0.f ? x : 0.01f * x; }

// ---- k_proj: h = emb[inSen] @ W ; f_src/f_dst ; maxfd (atomic) ; hB (bf16 B-frags) ----
// hB layout: [colblk kb (256)][featgrp nf (8)][lane (64)][8 bf16]; lane = fx + 16*quad
// holds h^T[nf*16+fx][kb*32 + quad*8 + j], j=0..7.  Block = 16 rows (half a colblk).
__global__ __launch_bounds__(256) void k_proj(
    const int* __restrict__ inSen, const float* __restrict__ emb,
    const float* __restrict__ W, const float* __restrict__ a_src,
    const float* __restrict__ a_dst, float* __restrict__ f_src,
    float* __restrict__ f_dst, float* __restrict__ maxfd,
    unsigned short* __restrict__ hB)
{
    __shared__ float ht[16 * 132];
    const int t = threadIdx.x;
    const int f = t & 127, rh = t >> 7;     // feature, row-half (8 rows each)
    const int i0 = blockIdx.x * 16;

    int wd[8];
    #pragma unroll
    for (int r = 0; r < 8; ++r) wd[r] = inSen[i0 + rh * 8 + r];
    float h[8];
    #pragma unroll
    for (int r = 0; r < 8; ++r) h[r] = 0.f;

    for (int k4 = 0; k4 < 32; ++k4) {
        const float w0 = W[(k4 * 4 + 0) * WF + f];
        const float w1 = W[(k4 * 4 + 1) * WF + f];
        const float w2 = W[(k4 * 4 + 2) * WF + f];
        const float w3 = W[(k4 * 4 + 3) * WF + f];
        #pragma unroll
        for (int r = 0; r < 8; ++r) {
            float4 ev = ((const float4*)(emb + (size_t)wd[r] * 128))[k4];
            h[r] += ev.x * w0 + ev.y * w1 + ev.z * w2 + ev.w * w3;
        }
    }
    #pragma unroll
    for (int r = 0; r < 8; ++r) ht[(rh * 8 + r) * 132 + f] = h[r];
    __syncthreads();

    if (t < 16) {
        float s = 0.f, d = 0.f;
        for (int k4 = 0; k4 < 32; ++k4) {
            float4 hv = *(const float4*)(ht + t * 132 + k4 * 4);
            float4 as = ((const float4*)a_src)[k4];
            float4 ad = ((const float4*)a_dst)[k4];
            s += hv.x * as.x + hv.y * as.y + hv.z * as.z + hv.w * as.w;
            d += hv.x * ad.x + hv.y * ad.y + hv.z * ad.z + hv.w * ad.w;
        }
        f_src[i0 + t] = s;
        f_dst[i0 + t] = d;
        float dm = d;
        #pragma unroll
        for (int o = 1; o < 16; o <<= 1) dm = fmaxf(dm, __shfl_xor(dm, o));
        if (t == 0) atomicMaxF(maxfd, dm);
    }
    // hB fragment write: this block fills quads {half*2, half*2+1} of colblk kb
    {
        const int kb = blockIdx.x >> 1, half = blockIdx.x & 1;
        const int nf = t >> 5, l32 = t & 31;
        const int qloc = l32 >> 4, fx = l32 & 15;
        const int lane = (half * 2 + qloc) * 16 + fx;
        const float* hp = ht + (qloc * 8) * 132 + nf * 16 + fx;
        uint4 v;
        v.x = f2bf(hp[0 * 132]) | (f2bf(hp[1 * 132]) << 16);
        v.y = f2bf(hp[2 * 132]) | (f2bf(hp[3 * 132]) << 16);
        v.z = f2bf(hp[4 * 132]) | (f2bf(hp[5 * 132]) << 16);
        v.w = f2bf(hp[6 * 132]) | (f2bf(hp[7 * 132]) << 16);
        *(uint4*)(hB + ((size_t)kb * 8 + nf) * 512 + lane * 8) = v;
    }
}

// ---- adj chunk: 256 cols, lane owns 4 (int4). Mask word -> mrow (LDS), p-sum -> sum. --
static __device__ __forceinline__ void adj_chunk(
    int c, int4 a, const float* __restrict__ fdl, int lane, int row, int sl,
    float fs, float C, int shl,
    unsigned int* __restrict__ mrow, float& sum)
{
    const float4 f = *(const float4*)(fdl + c * 256 + 4 * lane);
    const bool m0 = a.x > 0, m1 = a.y > 0, m2 = a.z > 0, m3 = a.w > 0;
    float p0 = m0 ? __expf(lrelu(fs + f.x) - C) : 0.f;
    float p1 = m1 ? __expf(lrelu(fs + f.y) - C) : 0.f;
    float p2 = m2 ? __expf(lrelu(fs + f.z) - C) : 0.f;
    float p3 = m3 ? __expf(lrelu(fs + f.w) - C) : 0.f;
    unsigned int nib = (m0 ? 1u : 0u) | (m1 ? 2u : 0u) | (m2 ? 4u : 0u) | (m3 ? 8u : 0u);
    float ssum = p0 + p1 + p2 + p3;
    if (c == (row >> 8)) {                      // wave-uniform: diagonal lives here
        if (lane == ((row & 255) >> 2)) {
            const int jd = row & 3;
            const int aj = jd == 0 ? a.x : jd == 1 ? a.y : jd == 2 ? a.z : a.w;
            const float fj = jd == 0 ? f.x : jd == 1 ? f.y : jd == 2 ? f.z : f.w;
            const bool mo = aj > 0, mn = (aj + sl) > 0;
            if (mn != mo) {
                const float pd = __expf(lrelu(fs + fj) - C);
                if (mn) { nib |= 1u << jd; ssum += pd; }
                else    { nib &= ~(1u << jd); ssum -= pd; }
            }
        }
    }
    sum += ssum;
    // pack 8 lanes' nibbles -> one u32 mask word (bit = col%32), 8 words per 256-col chunk
    unsigned int v = nib << shl;
    v |= __shfl_xor(v, 1);
    v |= __shfl_xor(v, 2);
    v |= __shfl_xor(v, 4);
    if ((lane & 7) == 0) mrow[c * 8 + (lane >> 3)] = v;
}

// process one full adj row (32 chunks) with a pre-filled depth-8 register ring
static __device__ __forceinline__ float adj_row(
    const int* __restrict__ ap, const float* __restrict__ fdl,
    int lane, int row, int sl, float fs, float C, int shl,
    unsigned int* __restrict__ mrow,
    int4 a0, int4 a1, int4 a2, int4 a3, int4 a4, int4 a5, int4 a6, int4 a7)
{
    float sum = 0.f;
    #define ADJC(c, reg) adj_chunk((c), (reg), fdl, lane, row, sl, fs, C, shl, mrow, sum)
    #pragma unroll 1
    for (int g = 0; g < 24; g += 8) {
        ADJC(g + 0, a0); a0 = *(const int4*)(ap + (g +  8) * 256);
        ADJC(g + 1, a1); a1 = *(const int4*)(ap + (g +  9) * 256);
        ADJC(g + 2, a2); a2 = *(const int4*)(ap + (g + 10) * 256);
        ADJC(g + 3, a3); a3 = *(const int4*)(ap + (g + 11) * 256);
        ADJC(g + 4, a4); a4 = *(const int4*)(ap + (g + 12) * 256);
        ADJC(g + 5, a5); a5 = *(const int4*)(ap + (g + 13) * 256);
        ADJC(g + 6, a6); a6 = *(const int4*)(ap + (g + 14) * 256);
        ADJC(g + 7, a7); a7 = *(const int4*)(ap + (g + 15) * 256);
    }
    ADJC(24, a0); ADJC(25, a1); ADJC(26, a2); ADJC(27, a3);
    ADJC(28, a4); ADJC(29, a5); ADJC(30, a6); ADJC(31, a7);
    #undef ADJC
    return sum;
}

// ---- k_fused: adj scan + attention for one 16-row strip, all in one block. ------------
// Phase 1: 8 waves x 2 rows stream adj (ring-8 prefetch), mask -> LDS, 1/rowsum -> LDS.
// Phase 2: v4 K-loop (wave = 1024-col K-split), mask/invl from LDS, direct sent store,
// fused pool partial. LDS: red 64KB; fdl aliases red[0..3], mask aliases red[4..]
// (both dead before red's post-loop writes). 2 blocks/CU.
__global__ __launch_bounds__(512, 4) void k_fused(
    const int* __restrict__ adj, const int* __restrict__ slP,
    const float* __restrict__ f_src, const float* __restrict__ f_dst,
    const float* __restrict__ maxfd, const unsigned short* __restrict__ hB,
    float* __restrict__ att, float* __restrict__ sent, float* __restrict__ partial)
{
    __shared__ float red[8][2048];                       // 64 KB
    __shared__ float sums[16];
    float* fdl = &red[0][0];                             // 8192 f32 (phases 1-2)
    unsigned int* mask = (unsigned int*)&red[4][0];      // 16 x MSTRIDE u32 (phases 1-2)
    const int t = threadIdx.x, lane = t & 63, w = t >> 6;
    const int strip = blockIdx.x;                        // 512 strips
    const int i0 = strip * 16;

    // issue row-A adj ring FIRST (HBM latency hides under fdl stage + barrier)
    const int rowA = i0 + 2 * w;
    const int* __restrict__ apA = adj + (size_t)rowA * NR + 4 * lane;
    int4 a0 = *(const int4*)(apA + 0 * 256);
    int4 a1 = *(const int4*)(apA + 1 * 256);
    int4 a2 = *(const int4*)(apA + 2 * 256);
    int4 a3 = *(const int4*)(apA + 3 * 256);
    int4 a4 = *(const int4*)(apA + 4 * 256);
    int4 a5 = *(const int4*)(apA + 5 * 256);
    int4 a6 = *(const int4*)(apA + 6 * 256);
    int4 a7 = *(const int4*)(apA + 7 * 256);

    #pragma unroll
    for (int i = 0; i < 4; ++i)
        *(float4*)(fdl + (i * 512 + t) * 4) = *(const float4*)(f_dst + (i * 512 + t) * 4);

    const int sl = slP[0];
    const float mfd = maxfd[0];
    const int shl = 4 * (lane & 7);
    __syncthreads();

    // ---- phase 1: this wave's two rows ----
    {
        const float fsA = f_src[rowA];
        const float CA = lrelu(fsA + mfd);
        float s = adj_row(apA, fdl, lane, rowA, sl, fsA, CA, shl,
                          mask + (2 * w) * MSTRIDE, a0, a1, a2, a3, a4, a5, a6, a7);
        #pragma unroll
        for (int o = 1; o < 64; o <<= 1) s += __shfl_xor(s, o);
        if (lane == 0) sums[2 * w] = 1.0f / s;
    }
    {
        const int rowB = i0 + 2 * w + 1;
        const int* __restrict__ apB = adj + (size_t)rowB * NR + 4 * lane;
        int4 b0 = *(const int4*)(apB + 0 * 256);
        int4 b1 = *(const int4*)(apB + 1 * 256);
        int4 b2 = *(const int4*)(apB + 2 * 256);
        int4 b3 = *(const int4*)(apB + 3 * 256);
        int4 b4 = *(const int4*)(apB + 4 * 256);
        int4 b5 = *(const int4*)(apB + 5 * 256);
        int4 b6 = *(const int4*)(apB + 6 * 256);
        int4 b7 = *(const int4*)(apB + 7 * 256);
        const float fsB = f_src[rowB];
        const float CB = lrelu(fsB + mfd);
        float s = adj_row(apB, fdl, lane, rowB, sl, fsB, CB, shl,
                          mask + (2 * w + 1) * MSTRIDE, b0, b1, b2, b3, b4, b5, b6, b7);
        #pragma unroll
        for (int o = 1; o < 64; o <<= 1) s += __shfl_xor(s, o);
        if (lane == 0) sums[2 * w + 1] = 1.0f / s;
    }
    __syncthreads();

    // ---- phase 2: K-loop (v4 structure), mask/invl from LDS ----
    const int fx = lane & 15, quad = lane >> 4;
    const int row = i0 + fx;
    const float fs = f_src[row];
    const float C = lrelu(fs + mfd);
    const float il = sums[fx];
    float* __restrict__ ar = att + (size_t)row * NR;
    const unsigned int* __restrict__ mrow = mask + fx * MSTRIDE;
    f32x4 acc[8] = {};
    const int k0 = w * 1024;

    for (int kk4 = k0; kk4 < k0 + 1024; kk4 += 128) {
        const uint4 mw = *(const uint4*)(mrow + (kk4 >> 5));     // LDS, 2-way bank = free
        const unsigned int mwa[4] = {mw.x, mw.y, mw.z, mw.w};
        #pragma unroll
        for (int j4 = 0; j4 < 4; ++j4) {
            const int kk = kk4 + j4 * 32;
            const int kb = kk >> 5;
            const unsigned short* hp = hB + (size_t)kb * 4096 + lane * 8;
            bf16x8 bfr[8];
            #pragma unroll
            for (int nf = 0; nf < 8; ++nf) bfr[nf] = *(const bf16x8*)(hp + nf * 512);

            const unsigned int mbyte = (mwa[j4] >> (quad * 8)) & 0xffu;
            const float4 fd0 = *(const float4*)(fdl + kk + quad * 8);     // LDS broadcast
            const float4 fd1 = *(const float4*)(fdl + kk + quad * 8 + 4);
            const float fv[8] = {fd0.x, fd0.y, fd0.z, fd0.w, fd1.x, fd1.y, fd1.z, fd1.w};
            float p[8];
            #pragma unroll
            for (int j = 0; j < 8; ++j)
                p[j] = ((mbyte >> j) & 1u) ? __expf(lrelu(fs + fv[j]) - C) : 0.f;

            const float4 w0 = make_float4(p[0] * il, p[1] * il, p[2] * il, p[3] * il);
            const float4 w1 = make_float4(p[4] * il, p[5] * il, p[6] * il, p[7] * il);
            *(float4*)(ar + kk + quad * 8) = w0;
            *(float4*)(ar + kk + quad * 8 + 4) = w1;

            union { uint4 u; bf16x8 v; } cv;
            cv.u.x = f2bf(p[0]) | (f2bf(p[1]) << 16);
            cv.u.y = f2bf(p[2]) | (f2bf(p[3]) << 16);
            cv.u.z = f2bf(p[4]) | (f2bf(p[5]) << 16);
            cv.u.w = f2bf(p[6]) | (f2bf(p[7]) << 16);
            #pragma unroll
            for (int nf = 0; nf < 8; ++nf)
                acc[nf] = __builtin_amdgcn_mfma_f32_16x16x32_bf16(cv.v, bfr[nf], acc[nf], 0, 0, 0);
        }
    }
    __syncthreads();                  // all fdl/mask reads done before red overwrites them
    // D layout (16x16x32): row = quad*4+reg (att row in strip), col = fx (feat in nf)
    #pragma unroll
    for (int reg = 0; reg < 4; ++reg) {
        #pragma unroll
        for (int nf = 0; nf < 8; ++nf)
            red[w][(quad * 4 + reg) * 128 + nf * 16 + fx] = acc[nf][reg];
    }
    __syncthreads();
    const int e0 = t * 4;                     // 512 threads x 4 = 2048 = 16 rows x 128
    const int m = e0 >> 7, f0 = e0 & 127;
    {
        const float vin = sums[m];
        float vv[4];
        #pragma unroll
        for (int j = 0; j < 4; ++j) {
            float s = 0.f;
            #pragma unroll
            for (int sx = 0; sx < 8; ++sx) s += red[sx][e0 + j];
            vv[j] = s * vin;
        }
        *(float4*)(sent + (size_t)(i0 + m) * WF + f0) = make_float4(vv[0], vv[1], vv[2], vv[3]);
        // stash vv in thread-exclusive slots (red[0][e0..e0+3] is read/written only by t)
        red[0][e0 + 0] = vv[0]; red[0][e0 + 1] = vv[1];
        red[0][e0 + 2] = vv[2]; red[0][e0 + 3] = vv[3];
    }
    __syncthreads();
    if (t < 128) {                            // column max over the strip's 16 rows
        float mx = red[0][t];
        #pragma unroll
        for (int mm = 1; mm < 16; ++mm) mx = fmaxf(mx, red[0][mm * 128 + t]);
        partial[strip * 128 + t] = mx;
    }
}

// ---- k_label: final pool max (512 strip partials) + classifier ------------------------
__global__ __launch_bounds__(128) void k_label(
    const float* __restrict__ partial, const float* __restrict__ cls_W,
    const float* __restrict__ cls_b, float* __restrict__ pool,
    float* __restrict__ label)
{
    __shared__ float s0[128], s1[128];
    const int t = threadIdx.x;
    float m0 = -1e30f, m1 = -1e30f, m2 = -1e30f, m3 = -1e30f;
    for (int b = 0; b < 512; b += 4) {
        m0 = fmaxf(m0, partial[(b + 0) * 128 + t]);
        m1 = fmaxf(m1, partial[(b + 1) * 128 + t]);
        m2 = fmaxf(m2, partial[(b + 2) * 128 + t]);
        m3 = fmaxf(m3, partial[(b + 3) * 128 + t]);
    }
    const float m = fmaxf(fmaxf(m0, m1), fmaxf(m2, m3));
    pool[t] = m;
    s0[t] = m * cls_W[t * 2 + 0];
    s1[t] = m * cls_W[t * 2 + 1];
    __syncthreads();
    if (t == 0) {
        float z0 = cls_b[0], z1 = cls_b[1];
        for (int f = 0; f < 128; ++f) { z0 += s0[f]; z1 += s1[f]; }
        float mm = fmaxf(z0, z1);
        float e0 = __expf(z0 - mm), e1 = __expf(z1 - mm);
        float inv = 1.0f / (e0 + e1);
        label[0] = e0 * inv;
        label[1] = e1 * inv;
    }
}

extern "C" void kernel_launch(void* const* d_in, const int* in_sizes, int n_in,
                              void* d_out, int out_size, void* d_ws, size_t ws_size,
                              hipStream_t stream)
{
    const int*   inSen    = (const int*)d_in[0];
    const int*   adj      = (const int*)d_in[1];
    const int*   selfLink = (const int*)d_in[2];
    const float* emb      = (const float*)d_in[3];
    const float* W        = (const float*)d_in[4];
    const float* a_src    = (const float*)d_in[5];
    const float* a_dst    = (const float*)d_in[6];
    const float* cls_W    = (const float*)d_in[7];
    const float* cls_b    = (const float*)d_in[8];

    float* out   = (float*)d_out;
    float* pool  = out;                         // 128
    float* att   = out + 128;                   // 8192*8192
    float* sent  = att + (size_t)NR * NR;       // 8192*128
    float* label = sent + (size_t)NR * WF;      // 2

    char* ws = (char*)d_ws;
    unsigned short* hB    = (unsigned short*)ws;               // 2 MB
    float* f_src   = (float*)(ws + (2u << 20));                // 32 KB
    float* f_dst   = f_src + NR;                               // 32 KB
    float* maxfd   = f_dst + NR;                               // 4 B (pad to 64)
    float* partial = maxfd + 64;                               // 512*128 = 256 KB

    hipMemsetAsync(maxfd, 0xFF, 4, stream);    // -NaN init for atomicMaxF
    k_proj<<<NR / 16, 256, 0, stream>>>(inSen, emb, W, a_src, a_dst, f_src, f_dst, maxfd, hB);
    k_fused<<<NR / 16, 512, 0, stream>>>(adj, selfLink, f_src, f_dst, maxfd, hB, att, sent, partial);
    k_label<<<1, 128, 0, stream>>>(partial, cls_W, cls_b, pool, label);
}